// Round 1
// baseline (244.926 us; speedup 1.0000x reference)
//
#include <hip/hip_runtime.h>
#include <cstdint>

#define B_  8
#define S_  2048
#define E_  1024
#define H_  128
#define NC_ 16          // chunks per sequence (S_/128)

typedef __attribute__((ext_vector_type(8))) short bf16x8;
typedef __attribute__((ext_vector_type(4))) float f32x4;

__device__ __forceinline__ short f2bf(float f){
  uint32_t u = __builtin_bit_cast(uint32_t, f);
  u = (u + 0x7fffu + ((u >> 16) & 1u)) >> 16;   // RNE
  return (short)u;
}
__device__ __forceinline__ float bf2f(short s){
  uint32_t u = ((uint32_t)(uint16_t)s) << 16;
  return __builtin_bit_cast(float, u);
}
__device__ __forceinline__ void load_lds16(const void* g, void* l){
  __builtin_amdgcn_global_load_lds(
    (const __attribute__((address_space(1))) void*)g,
    (__attribute__((address_space(3))) void*)l, 16, 0, 0);
}

// ---------------------------------------------------------------------------
// Kernel 1: W (E,H) f32 -> Wt (H,E) bf16, for all 3 weights (blockIdx.y)
// ---------------------------------------------------------------------------
__global__ __launch_bounds__(256) void wt_kernel(
    const float* __restrict__ WQ, const float* __restrict__ WK,
    const float* __restrict__ WV,
    short* __restrict__ WtQ, short* __restrict__ WtK, short* __restrict__ WtV)
{
  int which = blockIdx.y;
  const float* W = which == 0 ? WQ : which == 1 ? WK : WV;
  short* Wt      = which == 0 ? WtQ : which == 1 ? WtK : WtV;
  int base = blockIdx.x * 4096;
  #pragma unroll
  for (int t = 0; t < 16; t++){
    int idx = base + t * 256 + threadIdx.x;   // output index: n*1024 + kk
    int n  = idx >> 10;
    int kk = idx & 1023;
    Wt[idx] = f2bf(W[kk * H_ + n]);
  }
}

// ---------------------------------------------------------------------------
// Kernel 2: projections P = X @ W  (X fp32 16384x1024, Wt bf16 128x1024)
// 128x128 tile per block, BK=32, bf16 MFMA 16x16x32, fp32 A staged via DMA
// ---------------------------------------------------------------------------
__global__ __launch_bounds__(256) void proj_kernel(
    const float* __restrict__ Xq, const float* __restrict__ Xk,
    const float* __restrict__ Xv,
    const short* __restrict__ Wtq, const short* __restrict__ Wtk,
    const short* __restrict__ Wtv,
    short* __restrict__ Pq, short* __restrict__ Pk, short* __restrict__ Pv)
{
  int which = blockIdx.y;
  const float* X  = which == 0 ? Xq  : which == 1 ? Xk  : Xv;
  const short* Wt = which == 0 ? Wtq : which == 1 ? Wtk : Wtv;
  short* P        = which == 0 ? Pq  : which == 1 ? Pk  : Pv;

  __shared__ float As[128 * 32];   // [row][k] f32, 16 KB (DMA: must stay unpadded)
  __shared__ short Bs[128 * 32];   // [n][k] bf16, 8 KB

  int tid  = threadIdx.x;
  int lane = tid & 63;
  int wave = tid >> 6;
  int wrow = (wave >> 1) * 64, wcol = (wave & 1) * 64;
  int lr = lane & 15, lq = lane >> 4;
  int row0 = blockIdx.x * 128;

  f32x4 acc[4][4];
  #pragma unroll
  for (int a = 0; a < 4; a++)
    #pragma unroll
    for (int c = 0; c < 4; c++) acc[a][c] = (f32x4){0.f, 0.f, 0.f, 0.f};

  for (int k0 = 0; k0 < E_; k0 += 32){
    __syncthreads();
    // stage A: 128 rows x 32 f32; 1024B/instr = 8 rows; 4 instr per wave
    #pragma unroll
    for (int i = 0; i < 4; i++){
      int r = wave * 32 + i * 8 + (lane >> 3);
      int c = (lane & 7) * 4;
      load_lds16(X + (size_t)(row0 + r) * E_ + k0 + c,
                 (void*)(As + (wave * 32 + i * 8) * 32));
    }
    // stage B: 128 n-rows x 32 bf16 (64B rows); 16 rows/instr; 2 per wave
    #pragma unroll
    for (int i = 0; i < 2; i++){
      int nr = wave * 32 + i * 16 + (lane >> 2);
      int c  = (lane & 3) * 8;
      load_lds16(Wt + (size_t)nr * E_ + k0 + c,
                 (void*)(Bs + (wave * 32 + i * 16) * 32));
    }
    __syncthreads();

    bf16x8 af[4], bf[4];
    #pragma unroll
    for (int tm = 0; tm < 4; tm++){
      const float* ap = As + (wrow + tm * 16 + lr) * 32 + lq * 8;
      f32x4 lo = *(const f32x4*)ap;
      f32x4 hi = *(const f32x4*)(ap + 4);
      bf16x8 a;
      #pragma unroll
      for (int j = 0; j < 4; j++){ a[j] = f2bf(lo[j]); a[4 + j] = f2bf(hi[j]); }
      af[tm] = a;
    }
    #pragma unroll
    for (int tn = 0; tn < 4; tn++)
      bf[tn] = *(const bf16x8*)(Bs + (wcol + tn * 16 + lr) * 32 + lq * 8);

    #pragma unroll
    for (int tm = 0; tm < 4; tm++)
      #pragma unroll
      for (int tn = 0; tn < 4; tn++)
        acc[tm][tn] = __builtin_amdgcn_mfma_f32_16x16x32_bf16(
            af[tm], bf[tn], acc[tm][tn], 0, 0, 0);
  }

  // epilogue: C/D layout col=lane&15, row=(lane>>4)*4+reg
  #pragma unroll
  for (int tm = 0; tm < 4; tm++)
    #pragma unroll
    for (int tn = 0; tn < 4; tn++)
      #pragma unroll
      for (int r4 = 0; r4 < 4; r4++){
        int row = row0 + wrow + tm * 16 + lq * 4 + r4;
        int col = wcol + tn * 16 + lr;
        P[(size_t)row * H_ + col] = f2bf(acc[tm][tn][r4]);
      }
}

// ---------------------------------------------------------------------------
// Kernel 3: transpose k,v (B,S,H) -> kT,vT (B,H,S), bf16, 32x32 LDS tiles
// ---------------------------------------------------------------------------
__global__ __launch_bounds__(256) void transpose2(
    const short* __restrict__ k, const short* __restrict__ v,
    short* __restrict__ kT, short* __restrict__ vT)
{
  int b = blockIdx.z & 7;
  int which = blockIdx.z >> 3;
  const short* src = which ? v : k;
  short* dst       = which ? vT : kT;
  src += (size_t)b * S_ * H_;
  dst += (size_t)b * H_ * S_;
  int s0 = blockIdx.x * 32, h0 = blockIdx.y * 32;

  __shared__ short t[32][33];
  int tx = threadIdx.x & 31, ty = threadIdx.x >> 5;
  #pragma unroll
  for (int i = 0; i < 4; i++)
    t[ty + i * 8][tx] = src[(size_t)(s0 + ty + i * 8) * H_ + h0 + tx];
  __syncthreads();
  #pragma unroll
  for (int i = 0; i < 4; i++)
    dst[(size_t)(h0 + ty + i * 8) * S_ + s0 + tx] = t[tx][ty + i * 8];
}

// ---------------------------------------------------------------------------
// Kernel 4: per-chunk state M_j[h'][h] = sum_t V[t][h'] K[t][h]   (f32 out)
// ---------------------------------------------------------------------------
__global__ __launch_bounds__(256) void chunk_state(
    const short* __restrict__ vT, const short* __restrict__ kT,
    float* __restrict__ M)
{
  int j = blockIdx.x, b = blockIdx.y;
  int tid = threadIdx.x, lane = tid & 63, wave = tid >> 6;
  int wrow = (wave >> 1) * 64, wcol = (wave & 1) * 64;
  int lr = lane & 15, lq = lane >> 4;

  __shared__ short As[128 * 32];
  __shared__ short Bs[128 * 32];

  const short* vtb = vT + (size_t)b * H_ * S_ + j * 128;
  const short* ktb = kT + (size_t)b * H_ * S_ + j * 128;

  f32x4 acc[4][4];
  #pragma unroll
  for (int a = 0; a < 4; a++)
    #pragma unroll
    for (int c = 0; c < 4; c++) acc[a][c] = (f32x4){0.f, 0.f, 0.f, 0.f};

  for (int t0 = 0; t0 < 128; t0 += 32){
    __syncthreads();
    #pragma unroll
    for (int i = 0; i < 2; i++){
      int r = wave * 32 + i * 16 + (lane >> 2);
      int c = (lane & 3) * 8;
      load_lds16(vtb + (size_t)r * S_ + t0 + c,
                 (void*)(As + (wave * 32 + i * 16) * 32));
      load_lds16(ktb + (size_t)r * S_ + t0 + c,
                 (void*)(Bs + (wave * 32 + i * 16) * 32));
    }
    __syncthreads();
    bf16x8 af[4], bf[4];
    #pragma unroll
    for (int tm = 0; tm < 4; tm++)
      af[tm] = *(const bf16x8*)(As + (wrow + tm * 16 + lr) * 32 + lq * 8);
    #pragma unroll
    for (int tn = 0; tn < 4; tn++)
      bf[tn] = *(const bf16x8*)(Bs + (wcol + tn * 16 + lr) * 32 + lq * 8);
    #pragma unroll
    for (int tm = 0; tm < 4; tm++)
      #pragma unroll
      for (int tn = 0; tn < 4; tn++)
        acc[tm][tn] = __builtin_amdgcn_mfma_f32_16x16x32_bf16(
            af[tm], bf[tn], acc[tm][tn], 0, 0, 0);
  }

  float* mb = M + (size_t)(b * NC_ + j) * 16384;
  #pragma unroll
  for (int tm = 0; tm < 4; tm++)
    #pragma unroll
    for (int tn = 0; tn < 4; tn++)
      #pragma unroll
      for (int r4 = 0; r4 < 4; r4++){
        int row = wrow + tm * 16 + lq * 4 + r4;
        int col = wcol + tn * 16 + lr;
        mb[row * 128 + col] = acc[tm][tn][r4];
      }
}

// ---------------------------------------------------------------------------
// Kernel 5: exclusive prefix of M over chunks -> bf16 hi + residual lo
// ---------------------------------------------------------------------------
__global__ __launch_bounds__(256) void prefix_state(
    const float* __restrict__ M, short* __restrict__ Shi, short* __restrict__ Slo)
{
  int b = blockIdx.y;
  int idx = (blockIdx.x * 256 + threadIdx.x) * 4;
  float r0 = 0.f, r1 = 0.f, r2 = 0.f, r3 = 0.f;
  for (int j = 0; j < NC_; j++){
    size_t o = (size_t)(b * NC_ + j) * 16384 + idx;
    short h0 = f2bf(r0), h1 = f2bf(r1), h2 = f2bf(r2), h3 = f2bf(r3);
    short l0 = f2bf(r0 - bf2f(h0)), l1 = f2bf(r1 - bf2f(h1));
    short l2 = f2bf(r2 - bf2f(h2)), l3 = f2bf(r3 - bf2f(h3));
    union { short s[4]; uint2 u; } ph, pl;
    ph.s[0] = h0; ph.s[1] = h1; ph.s[2] = h2; ph.s[3] = h3;
    pl.s[0] = l0; pl.s[1] = l1; pl.s[2] = l2; pl.s[3] = l3;
    *(uint2*)(Shi + o) = ph.u;
    *(uint2*)(Slo + o) = pl.u;
    float4 mv = *(const float4*)(M + o);
    r0 += mv.x; r1 += mv.y; r2 += mv.z; r3 += mv.w;
  }
}

// ---------------------------------------------------------------------------
// Kernel 6: per (b, chunk i):
//   O = (Q_i K_i^T . tril) V_i + Q_i (State_hi + State_lo)
// ---------------------------------------------------------------------------
__global__ __launch_bounds__(256) void passC(
    const short* __restrict__ qb, const short* __restrict__ kb,
    const short* __restrict__ vT, const short* __restrict__ Shi,
    const short* __restrict__ Slo, float* __restrict__ out)
{
  int i = blockIdx.x, b = blockIdx.y;
  int tid = threadIdx.x, lane = tid & 63, wave = tid >> 6;
  int wrow = (wave >> 1) * 64, wcol = (wave & 1) * 64;
  int lr = lane & 15, lq = lane >> 4;

  __shared__ short Qs[128 * 136];   // padded stride 136 (conflict-free a-frag)
  __shared__ short Ss[128 * 136];
  __shared__ short Bsh[128 * 32];   // DMA staging (unpadded)

  const short* qbase = qb + ((size_t)b * S_ + i * 128) * H_;
  const short* kbase = kb + ((size_t)b * S_ + i * 128) * H_;
  const short* vtb   = vT + (size_t)b * H_ * S_ + i * 128;
  const short* shib  = Shi + (size_t)(b * NC_ + i) * 16384;
  const short* slob  = Slo + (size_t)(b * NC_ + i) * 16384;

  // stage Q into padded LDS (register path; 16B chunks)
  #pragma unroll
  for (int t = 0; t < 8; t++){
    int chunk = t * 256 + tid;           // 2048 chunks of 16B
    int s = chunk >> 4, c16 = chunk & 15;
    *(uint4*)(Qs + s * 136 + c16 * 8) =
        *(const uint4*)(qbase + s * H_ + c16 * 8);
  }

  f32x4 acc[4][4];
  #pragma unroll
  for (int a = 0; a < 4; a++)
    #pragma unroll
    for (int c = 0; c < 4; c++) acc[a][c] = (f32x4){0.f, 0.f, 0.f, 0.f};

  // ---- phase 1: S = Q K^T (k-dim = h) ----
  for (int h0 = 0; h0 < H_; h0 += 32){
    __syncthreads();
    #pragma unroll
    for (int t = 0; t < 2; t++){
      int r = wave * 32 + t * 16 + (lane >> 2);
      int c = (lane & 3) * 8;
      load_lds16(kbase + (size_t)r * H_ + h0 + c,
                 (void*)(Bsh + (wave * 32 + t * 16) * 32));
    }
    __syncthreads();
    bf16x8 af[4], bf[4];
    #pragma unroll
    for (int tm = 0; tm < 4; tm++)
      af[tm] = *(const bf16x8*)(Qs + (wrow + tm * 16 + lr) * 136 + h0 + lq * 8);
    #pragma unroll
    for (int tn = 0; tn < 4; tn++)
      bf[tn] = *(const bf16x8*)(Bsh + (wcol + tn * 16 + lr) * 32 + lq * 8);
    #pragma unroll
    for (int tm = 0; tm < 4; tm++)
      #pragma unroll
      for (int tn = 0; tn < 4; tn++)
        acc[tm][tn] = __builtin_amdgcn_mfma_f32_16x16x32_bf16(
            af[tm], bf[tn], acc[tm][tn], 0, 0, 0);
  }
  __syncthreads();

  // ---- phase 2: causal mask + bf16 -> Ss; zero acc for O ----
  #pragma unroll
  for (int tm = 0; tm < 4; tm++)
    #pragma unroll
    for (int tn = 0; tn < 4; tn++)
      #pragma unroll
      for (int r4 = 0; r4 < 4; r4++){
        int row = wrow + tm * 16 + lq * 4 + r4;
        int col = wcol + tn * 16 + lr;
        float vv = (col <= row) ? acc[tm][tn][r4] : 0.f;
        Ss[row * 136 + col] = f2bf(vv);
      }
  #pragma unroll
  for (int a = 0; a < 4; a++)
    #pragma unroll
    for (int c = 0; c < 4; c++) acc[a][c] = (f32x4){0.f, 0.f, 0.f, 0.f};
  __syncthreads();

  // ---- phase 3a: O += S V (k-dim = t); B operand from vT rows ----
  for (int t0 = 0; t0 < 128; t0 += 32){
    __syncthreads();
    #pragma unroll
    for (int t = 0; t < 2; t++){
      int r = wave * 32 + t * 16 + (lane >> 2);
      int c = (lane & 3) * 8;
      load_lds16(vtb + (size_t)r * S_ + t0 + c,
                 (void*)(Bsh + (wave * 32 + t * 16) * 32));
    }
    __syncthreads();
    bf16x8 af[4], bf[4];
    #pragma unroll
    for (int tm = 0; tm < 4; tm++)
      af[tm] = *(const bf16x8*)(Ss + (wrow + tm * 16 + lr) * 136 + t0 + lq * 8);
    #pragma unroll
    for (int tn = 0; tn < 4; tn++)
      bf[tn] = *(const bf16x8*)(Bsh + (wcol + tn * 16 + lr) * 32 + lq * 8);
    #pragma unroll
    for (int tm = 0; tm < 4; tm++)
      #pragma unroll
      for (int tn = 0; tn < 4; tn++)
        acc[tm][tn] = __builtin_amdgcn_mfma_f32_16x16x32_bf16(
            af[tm], bf[tn], acc[tm][tn], 0, 0, 0);
  }

  // ---- phase 3b: O += Q * State (hi then lo residual), k-dim = h ----
  #pragma unroll
  for (int part = 0; part < 2; part++){
    const short* sb = part == 0 ? shib : slob;
    for (int h0 = 0; h0 < H_; h0 += 32){
      __syncthreads();
      #pragma unroll
      for (int t = 0; t < 2; t++){
        int r = wave * 32 + t * 16 + (lane >> 2);
        int c = (lane & 3) * 8;
        load_lds16(sb + (size_t)r * 128 + h0 + c,
                   (void*)(Bsh + (wave * 32 + t * 16) * 32));
      }
      __syncthreads();
      bf16x8 af[4], bf[4];
      #pragma unroll
      for (int tm = 0; tm < 4; tm++)
        af[tm] = *(const bf16x8*)(Qs + (wrow + tm * 16 + lr) * 136 + h0 + lq * 8);
      #pragma unroll
      for (int tn = 0; tn < 4; tn++)
        bf[tn] = *(const bf16x8*)(Bsh + (wcol + tn * 16 + lr) * 32 + lq * 8);
      #pragma unroll
      for (int tm = 0; tm < 4; tm++)
        #pragma unroll
        for (int tn = 0; tn < 4; tn++)
          acc[tm][tn] = __builtin_amdgcn_mfma_f32_16x16x32_bf16(
              af[tm], bf[tn], acc[tm][tn], 0, 0, 0);
    }
  }

  // ---- epilogue ----
  float* ob = out + ((size_t)b * S_ + i * 128) * H_;
  #pragma unroll
  for (int tm = 0; tm < 4; tm++)
    #pragma unroll
    for (int tn = 0; tn < 4; tn++)
      #pragma unroll
      for (int r4 = 0; r4 < 4; r4++){
        int row = wrow + tm * 16 + lq * 4 + r4;
        int col = wcol + tn * 16 + lr;
        ob[(size_t)row * H_ + col] = acc[tm][tn][r4];
      }
}

// ---------------------------------------------------------------------------
extern "C" void kernel_launch(void* const* d_in, const int* in_sizes, int n_in,
                              void* d_out, int out_size, void* d_ws, size_t ws_size,
                              hipStream_t stream) {
  // setup_inputs order: key, query, value, W_Q, W_K, W_V (all fp32)
  const float* key   = (const float*)d_in[0];
  const float* query = (const float*)d_in[1];
  const float* value = (const float*)d_in[2];
  const float* WQ    = (const float*)d_in[3];
  const float* WK    = (const float*)d_in[4];
  const float* WV    = (const float*)d_in[5];
  float* out = (float*)d_out;

  char* w = (char*)d_ws;
  short* WtQ = (short*)(w + 0);                       // 3 x 256 KB
  short* WtK = (short*)(w + 262144);
  short* WtV = (short*)(w + 524288);
  size_t o = 786432;
  short* q  = (short*)(w + o); o += 4194304;          // (B,S,H) bf16
  short* k  = (short*)(w + o); o += 4194304;
  short* v  = (short*)(w + o); o += 4194304;
  short* kT = (short*)(w + o); o += 4194304;          // (B,H,S) bf16
  short* vT = (short*)(w + o); o += 4194304;
  float* M  = (float*)(w + o); o += 8388608;          // (B,NC,128,128) f32
  short* Shi= (short*)(w + o); o += 4194304;          // exclusive prefix, bf16 hi
  short* Slo= (short*)(w + o); o += 4194304;          // bf16 residual

  wt_kernel   <<<dim3(32, 3),          256, 0, stream>>>(WQ, WK, WV, WtQ, WtK, WtV);
  proj_kernel <<<dim3(128, 3),         256, 0, stream>>>(query, key, value,
                                                         WtQ, WtK, WtV, q, k, v);
  transpose2  <<<dim3(64, 4, 16),      256, 0, stream>>>(k, v, kT, vT);
  chunk_state <<<dim3(NC_, B_),        256, 0, stream>>>(vT, kT, M);
  prefix_state<<<dim3(16, B_),         256, 0, stream>>>(M, Shi, Slo);
  passC       <<<dim3(NC_, B_),        256, 0, stream>>>(q, k, vT, Shi, Slo, out);
}